// Round 3
// baseline (71.954 us; speedup 1.0000x reference)
//
#include <hip/hip_runtime.h>
#include <math.h>

namespace {
constexpr int NB = 512;   // batches
constexpr int NK = 1024;  // tokens per batch
constexpr int NM = 64;    // interests per batch
constexpr int ND = 128;   // feature dim
constexpr float ALPHA_T_TO_I = 0.3f;
constexpr int HALVES = 2;             // blocks per batch
constexpr int NBLK = NB * HALVES;     // 1024 blocks
constexpr int KPB = NK / HALVES;      // 512 tokens per block
constexpr int KPW = KPB / 4;          // 128 tokens per wave
constexpr int NT = KPW / 16;          // 8 tiles of 16 rows per wave
}

typedef __attribute__((ext_vector_type(8))) short short8;   // 8 bf16 — MFMA A/B frag
typedef __attribute__((ext_vector_type(4))) short short4v;  // 8 B LDS store
typedef __attribute__((ext_vector_type(4))) float f32x4;    // MFMA C/D frag

// fp32 -> bf16 round-to-nearest-even
__device__ __forceinline__ short f2bf(float f) {
  unsigned u = __builtin_bit_cast(unsigned, f);
  unsigned r = u + 0x7FFFu + ((u >> 16) & 1u);
  return (short)(r >> 16);
}

// 2 blocks per batch (1024 blocks, XCD-contiguous remap), 4 waves each.
// Interests: normalized bf16 in LDS once, 16 B-frags hoisted to VGPRs.
// Tokens: double-buffered register tiles straight from HBM (next tile's 8
// loads in flight across current tile's compute), normalized in-register,
// 16 MFMAs per 16-token tile. Raw max-dots written out; dist/sqrt deferred.
__global__ __launch_bounds__(256, 2) void chamfer_mfma(
    const float* __restrict__ tokens,
    const float* __restrict__ interests,
    float* __restrict__ colPart,   // [NBLK][NM] raw max-dot per (block, interest)
    float* __restrict__ rowPart)   // [NBLK]    sum over block's tokens of min-dist
{
  // XCD-contiguous work remap: XCD x handles 128 consecutive work-ids
  // (64 batches -> both halves + interests L2-resident, 2 MB/XCD).
  const int d    = blockIdx.x;
  const int bb   = (d & 7) * (NBLK / 8) + (d >> 3);
  const int b    = bb >> 1;
  const int half = bb & 1;
  const int tid  = threadIdx.x;
  const int lane = tid & 63;
  const int wave = tid >> 6;

  __shared__ __align__(16) short iLds[NM * ND];  // normalized interests bf16 (16 KB)
  __shared__ float colW[4][4][16];
  __shared__ float rowW[4];

  const float* __restrict__ ib = interests + (size_t)b * NM * ND;
  const float* __restrict__ tb = tokens    + (size_t)b * NK * ND;

  // ---- Phase 0: interests -> row-normalize -> bf16 LDS ----
  for (int it = 0; it < (NM * ND / 4) / 256; ++it) {   // 8 iters
    const int idx = it * 256 + tid;                    // float4 index; row = idx>>5
    const float4 v = reinterpret_cast<const float4*>(ib)[idx];
    float s = fmaf(v.x, v.x, fmaf(v.y, v.y, fmaf(v.z, v.z, v.w * v.w)));
    s += __shfl_xor(s, 1);  s += __shfl_xor(s, 2);  s += __shfl_xor(s, 4);
    s += __shfl_xor(s, 8);  s += __shfl_xor(s, 16);
    const float rn = 1.0f / fmaxf(sqrtf(s), 1e-12f);
    short4v o;
    o.x = f2bf(v.x * rn); o.y = f2bf(v.y * rn);
    o.z = f2bf(v.z * rn); o.w = f2bf(v.w * rn);
    reinterpret_cast<short4v*>(iLds)[idx] = o;
  }
  __syncthreads();

  // ---- Hoist all 16 B-fragments into VGPRs ----
  // Lane holds I_hat[c*16 + (lane&15)][q*32 + (lane>>4)*8 + i].
  short8 bfr[4][4];
#pragma unroll
  for (int c = 0; c < 4; ++c)
#pragma unroll
    for (int q = 0; q < 4; ++q) {
      const int off = (c * 16 + (lane & 15)) * ND + q * 32 + ((lane >> 4) * 8);
      bfr[c][q] = *reinterpret_cast<const short8*>(&iLds[off]);
    }

  float colMax[4] = {-2.f, -2.f, -2.f, -2.f};
  float rowSum = 0.f;
  const int colOff = (lane >> 4) * 8;
  const int rowBase = half * KPB + wave * KPW + (lane & 15);

  auto loadTile = [&](float4 (&dst)[8], int rt) {
    const float* tp = tb + (size_t)(rowBase + rt * 16) * ND + colOff;
#pragma unroll
    for (int q = 0; q < 4; ++q) {
      dst[2 * q]     = *reinterpret_cast<const float4*>(tp + q * 32);
      dst[2 * q + 1] = *reinterpret_cast<const float4*>(tp + q * 32 + 4);
    }
  };

  auto computeTile = [&](const float4 (&v)[8]) {
    float ssq = 0.f;
#pragma unroll
    for (int j = 0; j < 8; ++j) {
      ssq = fmaf(v[j].x, v[j].x, ssq); ssq = fmaf(v[j].y, v[j].y, ssq);
      ssq = fmaf(v[j].z, v[j].z, ssq); ssq = fmaf(v[j].w, v[j].w, ssq);
    }
    ssq += __shfl_xor(ssq, 16);
    ssq += __shfl_xor(ssq, 32);
    const float rn = 1.0f / fmaxf(sqrtf(ssq), 1e-12f);

    short8 af[4];
#pragma unroll
    for (int q = 0; q < 4; ++q) {
      short8 a;
      a[0] = f2bf(v[2 * q].x * rn);     a[1] = f2bf(v[2 * q].y * rn);
      a[2] = f2bf(v[2 * q].z * rn);     a[3] = f2bf(v[2 * q].w * rn);
      a[4] = f2bf(v[2 * q + 1].x * rn); a[5] = f2bf(v[2 * q + 1].y * rn);
      a[6] = f2bf(v[2 * q + 1].z * rn); a[7] = f2bf(v[2 * q + 1].w * rn);
      af[q] = a;
    }

    f32x4 acc[4];
#pragma unroll
    for (int c = 0; c < 4; ++c) acc[c] = (f32x4){0.f, 0.f, 0.f, 0.f};
#pragma unroll
    for (int c = 0; c < 4; ++c)
#pragma unroll
      for (int q = 0; q < 4; ++q)
        acc[c] = __builtin_amdgcn_mfma_f32_16x16x32_bf16(af[q], bfr[c][q], acc[c], 0, 0, 0);

    // Row-max (token -> nearest interest): C row = (lane>>4)*4+i, col = lane&15 (+16c).
#pragma unroll
    for (int i = 0; i < 4; ++i) {
      float rm = fmaxf(fmaxf(acc[0][i], acc[1][i]), fmaxf(acc[2][i], acc[3][i]));
      rm = fmaxf(rm, __shfl_xor(rm, 1));
      rm = fmaxf(rm, __shfl_xor(rm, 2));
      rm = fmaxf(rm, __shfl_xor(rm, 4));
      rm = fmaxf(rm, __shfl_xor(rm, 8));
      if ((lane & 15) == 0)
        rowSum += sqrtf(fmaxf(2.0f - 2.0f * rm, 1e-12f));
    }
    // Col-max (interest -> nearest token) over this lane's 4 token rows.
#pragma unroll
    for (int c = 0; c < 4; ++c) {
      const float m01 = fmaxf(acc[c][0], acc[c][1]);
      const float m23 = fmaxf(acc[c][2], acc[c][3]);
      colMax[c] = fmaxf(colMax[c], fmaxf(m01, m23));
    }
  };

  // ---- Main loop: software-pipelined double buffer ----
  float4 A[8], B[8];
  loadTile(A, 0);
#pragma unroll 1
  for (int rt = 0; rt < NT; rt += 2) {
    loadTile(B, rt + 1);
    computeTile(A);
    if (rt + 2 < NT) loadTile(A, rt + 2);
    computeTile(B);
  }

  // Combine col-max across the wave's 4 row-groups.
#pragma unroll
  for (int c = 0; c < 4; ++c) {
    colMax[c] = fmaxf(colMax[c], __shfl_xor(colMax[c], 16));
    colMax[c] = fmaxf(colMax[c], __shfl_xor(colMax[c], 32));
  }
  if (lane < 16)
#pragma unroll
    for (int c = 0; c < 4; ++c) colW[wave][c][lane] = colMax[c];

  // Wave-total token dist sum (nonzero only on lanes 0,16,32,48).
  rowSum += __shfl_xor(rowSum, 1);  rowSum += __shfl_xor(rowSum, 2);
  rowSum += __shfl_xor(rowSum, 4);  rowSum += __shfl_xor(rowSum, 8);
  rowSum += __shfl_xor(rowSum, 16); rowSum += __shfl_xor(rowSum, 32);
  if (lane == 0) rowW[wave] = rowSum;
  __syncthreads();

  if (tid < NM) {  // m == tid: c = tid>>4, j = tid&15 -> m = c*16+j = tid
    const int c = tid >> 4, j = tid & 15;
    const float v = fmaxf(fmaxf(colW[0][c][j], colW[1][c][j]),
                          fmaxf(colW[2][c][j], colW[3][c][j]));
    colPart[bb * NM + tid] = v;  // raw max-dot; dist deferred to finalize
    if (tid == 0)
      rowPart[bb] = rowW[0] + rowW[1] + rowW[2] + rowW[3];
  }
}

// Deterministic final reduction: combine per-half max-dots, sqrt, flat sums.
__global__ __launch_bounds__(256) void chamfer_finalize(
    const float* __restrict__ colPart, const float* __restrict__ rowPart,
    float* __restrict__ out)
{
  __shared__ float s1s[256];
  __shared__ float s2s[256];
  const int t = threadIdx.x;
  float sCol = 0.f, sRow = 0.f;
  // colPart layout: [b][half][m] (bb = 2b+half). Pair (b*128+m, b*128+64+m).
#pragma unroll 4
  for (int i = 0; i < (NB * NM) / 256; ++i) {  // 128 iters
    const int p = t + 256 * i;
    const int b = p >> 6, m = p & 63;
    const float v = fmaxf(colPart[b * 128 + m], colPart[b * 128 + 64 + m]);
    sCol += sqrtf(fmaxf(2.0f - 2.0f * v, 1e-12f));
  }
#pragma unroll
  for (int i = 0; i < NBLK / 256; ++i)  // 4 iters
    sRow += rowPart[t + 256 * i];
  s1s[t] = sCol;
  s2s[t] = sRow;
  __syncthreads();
  for (int off = 128; off; off >>= 1) {
    if (t < off) { s1s[t] += s1s[t + off]; s2s[t] += s2s[t + off]; }
    __syncthreads();
  }
  if (t == 0) {
    const float loss_i_to_t = s1s[0] * (1.0f / (float)(NB * NM));
    const float loss_t_to_i = s2s[0] * (1.0f / (float)(NB * NK));
    out[0] = loss_i_to_t + ALPHA_T_TO_I * loss_t_to_i;
  }
}

extern "C" void kernel_launch(void* const* d_in, const int* in_sizes, int n_in,
                              void* d_out, int out_size, void* d_ws, size_t ws_size,
                              hipStream_t stream) {
  const float* tokens    = (const float*)d_in[0];  // (512, 1024, 128) f32
  const float* interests = (const float*)d_in[1];  // (512, 64, 128) f32
  float* colPart = (float*)d_ws;                    // NBLK*NM floats (256 KB)
  float* rowPart = colPart + (size_t)NBLK * NM;     // NBLK floats
  float* out     = (float*)d_out;

  chamfer_mfma<<<dim3(NBLK), dim3(256), 0, stream>>>(tokens, interests, colPart, rowPart);
  chamfer_finalize<<<dim3(1), dim3(256), 0, stream>>>(colPart, rowPart, out);
}

// Round 4
// 54.930 us; speedup vs baseline: 1.3099x; 1.3099x over previous
//
#include <hip/hip_runtime.h>
#include <math.h>

namespace {
constexpr int NB = 512;   // batches
constexpr int NK = 1024;  // tokens per batch
constexpr int NM = 64;    // interests per batch
constexpr int ND = 128;   // feature dim
constexpr float ALPHA_T_TO_I = 0.3f;
}

typedef __attribute__((ext_vector_type(8))) short short8;   // 8 bf16 — MFMA A/B frag
typedef __attribute__((ext_vector_type(4))) short short4v;  // 8 B LDS store
typedef __attribute__((ext_vector_type(4))) float f32x4;    // MFMA C/D frag

// fp32 -> bf16 round-to-nearest-even
__device__ __forceinline__ short f2bf(float f) {
  unsigned u = __builtin_bit_cast(unsigned, f);
  unsigned r = u + 0x7FFFu + ((u >> 16) & 1u);
  return (short)(r >> 16);
}

// One block per batch (512 blocks = exactly 2/CU), 4 waves. Wave w owns token
// rows [w*256, w*256+256). Interests: normalized bf16 in LDS once, 16 B-frags
// hoisted to VGPRs. Tokens: loaded straight from HBM in fragment order into a
// SINGLE 32-VGPR buffer; after the buffer is consumed (ssq + bf16 convert),
// the NEXT tile's 8 loads are issued into the same registers before the
// MFMA/reduction block — depth-1 prefetch at zero VGPR cost.
__global__ __launch_bounds__(256, 2) void chamfer_mfma(
    const float* __restrict__ tokens,
    const float* __restrict__ interests,
    float* __restrict__ partial)  // [b] = sum_m mindist ; [NB+b] = sum_k mindist
{
  const int b    = blockIdx.x;
  const int tid  = threadIdx.x;
  const int lane = tid & 63;
  const int wave = tid >> 6;

  __shared__ __align__(16) short iLds[NM * ND];  // normalized interests bf16 (16 KB)
  __shared__ float colW[4][4][16];
  __shared__ float rowW[4];

  const float* __restrict__ ib = interests + (size_t)b * NM * ND;
  const float* __restrict__ tb = tokens    + (size_t)b * NK * ND;

  const int colOff  = (lane >> 4) * 8;
  const int rowBase = wave * (NK / 4) + (lane & 15);

  // Prologue: issue tile 0's loads before phase 0 (independent of LDS work).
  float4 v[8];
  {
    const float* tp = tb + (size_t)rowBase * ND + colOff;
#pragma unroll
    for (int q = 0; q < 4; ++q) {
      v[2 * q]     = *reinterpret_cast<const float4*>(tp + q * 32);
      v[2 * q + 1] = *reinterpret_cast<const float4*>(tp + q * 32 + 4);
    }
  }

  // ---- Phase 0: interests -> row-normalize -> bf16 LDS ----
  for (int it = 0; it < (NM * ND / 4) / 256; ++it) {   // 8 iters
    const int idx = it * 256 + tid;                    // float4 index; row = idx>>5
    const float4 w = reinterpret_cast<const float4*>(ib)[idx];
    float s = fmaf(w.x, w.x, fmaf(w.y, w.y, fmaf(w.z, w.z, w.w * w.w)));
    s += __shfl_xor(s, 1);  s += __shfl_xor(s, 2);  s += __shfl_xor(s, 4);
    s += __shfl_xor(s, 8);  s += __shfl_xor(s, 16);
    const float rn = 1.0f / fmaxf(sqrtf(s), 1e-12f);
    short4v o;
    o.x = f2bf(w.x * rn); o.y = f2bf(w.y * rn);
    o.z = f2bf(w.z * rn); o.w = f2bf(w.w * rn);
    reinterpret_cast<short4v*>(iLds)[idx] = o;
  }
  __syncthreads();

  // ---- Hoist all 16 B-fragments into VGPRs ----
  // Lane holds I_hat[c*16 + (lane&15)][q*32 + (lane>>4)*8 + i].
  short8 bfr[4][4];
#pragma unroll
  for (int c = 0; c < 4; ++c)
#pragma unroll
    for (int q = 0; q < 4; ++q) {
      const int off = (c * 16 + (lane & 15)) * ND + q * 32 + ((lane >> 4) * 8);
      bfr[c][q] = *reinterpret_cast<const short8*>(&iLds[off]);
    }

  float colMax[4] = {-2.f, -2.f, -2.f, -2.f};
  float rowSum = 0.f;

#pragma unroll 1
  for (int rt = 0; rt < 16; ++rt) {
    // Consume v: row norm + bf16 A-fragments (v dead after this block).
    float ssq = 0.f;
#pragma unroll
    for (int j = 0; j < 8; ++j) {
      ssq = fmaf(v[j].x, v[j].x, ssq); ssq = fmaf(v[j].y, v[j].y, ssq);
      ssq = fmaf(v[j].z, v[j].z, ssq); ssq = fmaf(v[j].w, v[j].w, ssq);
    }
    ssq += __shfl_xor(ssq, 16);
    ssq += __shfl_xor(ssq, 32);
    const float rn = 1.0f / fmaxf(sqrtf(ssq), 1e-12f);

    short8 af[4];
#pragma unroll
    for (int q = 0; q < 4; ++q) {
      short8 a;
      a[0] = f2bf(v[2 * q].x * rn);     a[1] = f2bf(v[2 * q].y * rn);
      a[2] = f2bf(v[2 * q].z * rn);     a[3] = f2bf(v[2 * q].w * rn);
      a[4] = f2bf(v[2 * q + 1].x * rn); a[5] = f2bf(v[2 * q + 1].y * rn);
      a[6] = f2bf(v[2 * q + 1].z * rn); a[7] = f2bf(v[2 * q + 1].w * rn);
      af[q] = a;
    }

    // Depth-1 prefetch: next tile's loads into the same registers, issued
    // BEFORE the MFMA/reduction block so they fly during compute.
    if (rt + 1 < 16) {
      const float* tp = tb + (size_t)(rowBase + (rt + 1) * 16) * ND + colOff;
#pragma unroll
      for (int q = 0; q < 4; ++q) {
        v[2 * q]     = *reinterpret_cast<const float4*>(tp + q * 32);
        v[2 * q + 1] = *reinterpret_cast<const float4*>(tp + q * 32 + 4);
      }
    }

    f32x4 acc[4];
#pragma unroll
    for (int c = 0; c < 4; ++c) acc[c] = (f32x4){0.f, 0.f, 0.f, 0.f};
#pragma unroll
    for (int c = 0; c < 4; ++c)
#pragma unroll
      for (int q = 0; q < 4; ++q)
        acc[c] = __builtin_amdgcn_mfma_f32_16x16x32_bf16(af[q], bfr[c][q], acc[c], 0, 0, 0);

    // Row-max (token -> nearest interest): C row = (lane>>4)*4+i, col = lane&15 (+16c).
#pragma unroll
    for (int i = 0; i < 4; ++i) {
      float rm = fmaxf(fmaxf(acc[0][i], acc[1][i]), fmaxf(acc[2][i], acc[3][i]));
      rm = fmaxf(rm, __shfl_xor(rm, 1));
      rm = fmaxf(rm, __shfl_xor(rm, 2));
      rm = fmaxf(rm, __shfl_xor(rm, 4));
      rm = fmaxf(rm, __shfl_xor(rm, 8));
      if ((lane & 15) == 0)
        rowSum += sqrtf(fmaxf(2.0f - 2.0f * rm, 1e-12f));
    }
    // Col-max (interest -> nearest token) over this lane's 4 token rows.
#pragma unroll
    for (int c = 0; c < 4; ++c) {
      const float m01 = fmaxf(acc[c][0], acc[c][1]);
      const float m23 = fmaxf(acc[c][2], acc[c][3]);
      colMax[c] = fmaxf(colMax[c], fmaxf(m01, m23));
    }
  }

  // Combine col-max across the wave's 4 row-groups.
#pragma unroll
  for (int c = 0; c < 4; ++c) {
    colMax[c] = fmaxf(colMax[c], __shfl_xor(colMax[c], 16));
    colMax[c] = fmaxf(colMax[c], __shfl_xor(colMax[c], 32));
  }
  if (lane < 16)
#pragma unroll
    for (int c = 0; c < 4; ++c) colW[wave][c][lane] = colMax[c];

  // Wave-total token dist sum (nonzero only on lanes 0,16,32,48).
  rowSum += __shfl_xor(rowSum, 1);  rowSum += __shfl_xor(rowSum, 2);
  rowSum += __shfl_xor(rowSum, 4);  rowSum += __shfl_xor(rowSum, 8);
  rowSum += __shfl_xor(rowSum, 16); rowSum += __shfl_xor(rowSum, 32);
  if (lane == 0) rowW[wave] = rowSum;
  __syncthreads();

  if (tid < NM) {  // m == tid: c = tid>>4, j = tid&15 -> m = c*16+j = tid
    const int c = tid >> 4, j = tid & 15;
    const float v2 = fmaxf(fmaxf(colW[0][c][j], colW[1][c][j]),
                           fmaxf(colW[2][c][j], colW[3][c][j]));
    float dist = sqrtf(fmaxf(2.0f - 2.0f * v2, 1e-12f));
    dist += __shfl_xor(dist, 1);  dist += __shfl_xor(dist, 2);
    dist += __shfl_xor(dist, 4);  dist += __shfl_xor(dist, 8);
    dist += __shfl_xor(dist, 16); dist += __shfl_xor(dist, 32);
    if (tid == 0) {
      partial[b]      = dist;
      partial[NB + b] = rowW[0] + rowW[1] + rowW[2] + rowW[3];
    }
  }
}

// Deterministic final reduction over the 512 per-batch partials.
__global__ __launch_bounds__(256) void chamfer_finalize(
    const float* __restrict__ partial, float* __restrict__ out)
{
  __shared__ float s1s[256];
  __shared__ float s2s[256];
  const int t = threadIdx.x;
  s1s[t] = partial[t] + partial[t + 256];
  s2s[t] = partial[NB + t] + partial[NB + t + 256];
  __syncthreads();
  for (int off = 128; off; off >>= 1) {
    if (t < off) { s1s[t] += s1s[t + off]; s2s[t] += s2s[t + off]; }
    __syncthreads();
  }
  if (t == 0) {
    const float loss_i_to_t = s1s[0] * (1.0f / (float)(NB * NM));
    const float loss_t_to_i = s2s[0] * (1.0f / (float)(NB * NK));
    out[0] = loss_i_to_t + ALPHA_T_TO_I * loss_t_to_i;
  }
}

extern "C" void kernel_launch(void* const* d_in, const int* in_sizes, int n_in,
                              void* d_out, int out_size, void* d_ws, size_t ws_size,
                              hipStream_t stream) {
  const float* tokens    = (const float*)d_in[0];  // (512, 1024, 128) f32
  const float* interests = (const float*)d_in[1];  // (512, 64, 128) f32
  float* partial = (float*)d_ws;                   // 2*NB floats
  float* out     = (float*)d_out;

  chamfer_mfma<<<dim3(NB), dim3(256), 0, stream>>>(tokens, interests, partial);
  chamfer_finalize<<<dim3(1), dim3(256), 0, stream>>>(partial, out);
}